// Round 9
// baseline (180.194 us; speedup 1.0000x reference)
//
#include <hip/hip_runtime.h>
#include <math.h>

// MinGRU: B=8, S=8192, D=256, H=256, fp32 in/out.
//   K0 prep_w   : weights-only fp32->bf16 (256 KiB, ~3 us).
//   K1 gemm_zh  : bf16-MFMA dual GEMM, 512 thr / 128x128 tile / 8 waves.
//                 x packed inline; weights pure uint4 copy from bf16.
//                 Sigmoid epilogue + fused phase-A now emits BOTH
//                 16-step subchunk summaries (pqsub; P[i],Q[i] after the
//                 q-butterfly are exactly these) AND 64-step chunk
//                 summaries (chunkPQ). Epilogue register-trimmed (fold
//                 P,Q inside the i-loop; kills u[4][4] live range/spill).
//   K2 phaseB   : sequential scan over 128 chunk summaries (batch-16).
//   K3 phaseC   : replay; 1024 blocks x 256 thr = 16 waves/CU (4x R8's
//                 TLP). Wave g of a block handles subchunk g: fold <=3
//                 pqsub entries to get starting h (wave-uniform), then
//                 16-step replay at 16B/lane (uint4/float4).
// R8 lesson: 64-thr phaseC blocks = 4 waves/CU = latency-bound (~100us).
// R7 lesson: full x-prep is zero-sum -> x packs inline.
// R4 lessons: direct-L2 weight fragments stall MFMA (keep LDS staging);
//             512-long phaseB chain is slow (keep chunk-level phaseB);
//             subchunk composition numerics verified (passed, 0.03125).
// R1/R2 lesson: register-resident scan across a grid sync always spills.

constexpr int B_ = 8;
constexpr int S_ = 8192;
constexpr int D_ = 256;
constexpr int H_ = 256;
constexpr int M_ = B_ * S_;        // 65536 rows
constexpr int CHUNKS = 128;
constexpr int CLEN = S_ / CHUNKS;  // 64

typedef __attribute__((ext_vector_type(8))) short bf16x8;
typedef __attribute__((ext_vector_type(4))) float f32x4;

// 2 floats -> 2 bf16 (round-to-nearest, ties-away): 2 adds + 1 v_perm.
// lo16 = bf16(f0), hi16 = bf16(f1).
__device__ __forceinline__ uint pack2bf(float f0, float f1) {
  const uint u0 = __float_as_uint(f0) + 0x8000u;
  const uint u1 = __float_as_uint(f1) + 0x8000u;
  return __builtin_amdgcn_perm(u1, u0, 0x07060302u);
}

__device__ __forceinline__ float a_of(uint u) { return __uint_as_float(u << 16); }
__device__ __forceinline__ float b_of(uint u) { return __uint_as_float(u & 0xFFFF0000u); }

// ---------------------------------------------------------------- prep ----
// Weights only: 2 x 256x256 fp32 -> bf16 (identical pack2bf rounding).
__global__ __launch_bounds__(256) void prep_w(
    const float* __restrict__ wzw, const float* __restrict__ whw,
    uint4* __restrict__ wb)
{
  const int u = blockIdx.x * 256 + threadIdx.x;   // 0..16383 (8192 per proj)
  const int proj = u >> 13;
  const float* s = (proj ? whw : wzw) + (size_t)(u & 8191) * 8;
  wb[u] = make_uint4(pack2bf(s[0], s[1]), pack2bf(s[2], s[3]),
                     pack2bf(s[4], s[5]), pack2bf(s[6], s[7]));
}

// ---------------------------------------------------------------- GEMM ----
// Block: 512 thr = 8 waves. Tile: 128 rows x 128 h-channels, both proj.
// LDS rows padded to 72 bf16 (144B = 9x16B: uint4-aligned, conflict-free
// b128 fragment reads). Wave w: rows mb..mb+63 (one 64-step chunk),
// channels nb..nb+31 (nb = (w>>1)*32 over the 128-ch tile).
__global__ __launch_bounds__(512, 4) void gemm_zh(
    const float* __restrict__ x, const ushort* __restrict__ wbu,
    const float* __restrict__ whb, const float* __restrict__ wzb,
    uint* __restrict__ ab, float2* __restrict__ chunkPQ,
    float2* __restrict__ pqsub)
{
  __shared__ ushort xs[128][72];
  __shared__ ushort wzs[128][72];
  __shared__ ushort whs[128][72];

  const int tid = threadIdx.x;
  // XCD swizzle: the 2 n-tiles of a 128-row x-panel land on one XCD.
  const int g    = blockIdx.x;          // 0..1023
  const int xcd  = g & 7;
  const int loc  = g >> 3;              // 0..127
  const int nt   = loc & 1;
  const int panel = (loc >> 1) * 8 + xcd;  // 0..511
  const int m0 = panel * 128;
  const int n0 = nt * 128;

  const int lane = tid & 63;
  const int w  = tid >> 6;              // 0..7
  const int mb = (w & 1) * 64;
  const int nb = (w >> 1) * 32;         // 0,32,64,96
  const int q  = lane >> 4;
  const int cn = lane & 15;

  f32x4 accz[4][2] = {};
  f32x4 acch[4][2] = {};

  for (int k0 = 0; k0 < D_; k0 += 64) {
    __syncthreads();  // WAR guard on LDS reuse
#pragma unroll
    for (int f = 0; f < 4; f++) {  // x: 128 rows x 64 k, fp32 + inline pack
      const int idx = tid + 512 * f;
      const int row = idx >> 4, seg = idx & 15;
      float4 v = *(const float4*)(x + (size_t)(m0 + row) * D_ + k0 + seg * 4);
      *(uint2*)&xs[row][seg * 4] =
          make_uint2(pack2bf(v.x, v.y), pack2bf(v.z, v.w));
    }
#pragma unroll
    for (int f = 0; f < 4; f++) {  // weights: 128 ch x 64 k x 2 proj, copy
      const int idx = tid + 512 * f;
      const int proj = idx >> 10;        // f<2 -> 0, f>=2 -> 1 (uniform)
      const int r   = (idx >> 3) & 127, seg = idx & 7;
      const uint4 v = *(const uint4*)(wbu + (size_t)proj * H_ * D_ +
                                      (size_t)(n0 + r) * D_ + k0 + seg * 8);
      ushort* dst = proj ? &whs[r][seg * 8] : &wzs[r][seg * 8];
      *(uint4*)dst = v;
    }
    __syncthreads();
#pragma unroll
    for (int ks = 0; ks < 2; ks++) {
      const int kk = ks * 32 + q * 8;  // A[m=lane&15][k=quad*8+j]
      bf16x8 af[4], bz[2], bh[2];
#pragma unroll
      for (int i = 0; i < 4; i++)
        af[i] = *(const bf16x8*)&xs[mb + i * 16 + cn][kk];
#pragma unroll
      for (int j = 0; j < 2; j++) {
        bz[j] = *(const bf16x8*)&wzs[nb + j * 16 + cn][kk];
        bh[j] = *(const bf16x8*)&whs[nb + j * 16 + cn][kk];
      }
#pragma unroll
      for (int i = 0; i < 4; i++)
#pragma unroll
        for (int j = 0; j < 2; j++) {
          accz[i][j] = __builtin_amdgcn_mfma_f32_16x16x32_bf16(af[i], bz[j], accz[i][j], 0, 0, 0);
          acch[i][j] = __builtin_amdgcn_mfma_f32_16x16x32_bf16(af[i], bh[j], acch[i][j], 0, 0, 0);
        }
    }
  }

  // Chunk identity for this wave (chunks never cross batch: 8192%64==0).
  const int row0 = m0 + mb;
  const int bb2  = row0 >> 13;          // batch
  const int cc   = (row0 & 8191) >> 6;  // chunk within batch

  // Epilogue: C/D col=lane&15, row=quad*4+reg. a=1-z=e*rcp, b=z*h~.
  // t within chunk = i*16 + q*4 + r (ascending in i, q, r); so index i
  // selects the 16-step subchunk [i*16, i*16+16).
#pragma unroll
  for (int j = 0; j < 2; j++) {
    const int ch = n0 + nb + j * 16 + cn;
    const float zb = wzb[ch], hb = whb[ch];
    float P[4], Q[4];
#pragma unroll
    for (int i = 0; i < 4; i++) {
      float Pi = 1.f, Qi = 0.f;
#pragma unroll
      for (int r = 0; r < 4; r++) {
        const int row = m0 + mb + i * 16 + q * 4 + r;
        const float zpre = accz[i][j][r] + zb;
        const float hpre = acch[i][j][r] + hb;
        const float e = __expf(-zpre);
        const float rcp = __builtin_amdgcn_rcpf(1.0f + e);  // z
        const uint pk = pack2bf(e * rcp, hpre * rcp);
        ab[(size_t)row * H_ + ch] = pk;
        const float a  = a_of(pk);
        const float bv = b_of(pk);
        Qi = fmaf(a, Qi, bv);
        Pi *= a;
      }
      P[i] = Pi; Q[i] = Qi;
    }
    // combine(first,second): P = P1*P2, Q = fma(P2, Q1, Q2). t-order aware.
#pragma unroll
    for (int i = 0; i < 4; i++) {
      {  // partner q^1 (lane^16)
        const float Pp = __shfl_xor(P[i], 16);
        const float Qp = __shfl_xor(Q[i], 16);
        const bool later = (lane & 16) != 0;
        Q[i] = later ? fmaf(P[i], Qp, Q[i]) : fmaf(Pp, Q[i], Qp);
        P[i] = P[i] * Pp;
      }
      {  // partner q^2 (lane^32)
        const float Pp = __shfl_xor(P[i], 32);
        const float Qp = __shfl_xor(Q[i], 32);
        const bool later = (lane & 32) != 0;
        Q[i] = later ? fmaf(P[i], Qp, Q[i]) : fmaf(Pp, Q[i], Qp);
        P[i] = P[i] * Pp;
      }
    }
    // P[i],Q[i] = full summary of subchunk i. Fold -> chunk summary.
    float Pc = P[0], Qc = Q[0];
#pragma unroll
    for (int i = 1; i < 4; i++) {
      Qc = fmaf(P[i], Qc, Q[i]);
      Pc *= P[i];
    }
    if (lane < 16) {  // one lane per channel (cn==lane, q==0)
      const size_t sb = ((size_t)bb2 * CHUNKS + cc) * 4;
#pragma unroll
      for (int i = 0; i < 4; i++)
        pqsub[(sb + i) * H_ + ch] = make_float2(P[i], Q[i]);
      chunkPQ[((size_t)bb2 * CHUNKS + cc) * H_ + ch] = make_float2(Pc, Qc);
    }
  }
}

// ---------------------------------------------------------------- scans ---
// Phase B: sequential scan over chunk summaries, batch-16 float2 loads.
__global__ __launch_bounds__(256) void scan_phaseB(
    const float* __restrict__ h0in, const float2* __restrict__ pq,
    float* __restrict__ hstate)
{
  const int b = blockIdx.x;
  const int h = threadIdx.x;
  const size_t base = (size_t)b * CHUNKS * H_ + h;
  float hc = h0in[(size_t)b * H_ + h];
  for (int c0 = 0; c0 < CHUNKS; c0 += 16) {
    float2 v[16];
#pragma unroll
    for (int j = 0; j < 16; j++)
      v[j] = pq[base + (size_t)(c0 + j) * H_];
#pragma unroll
    for (int j = 0; j < 16; j++) {
      hstate[base + (size_t)(c0 + j) * H_] = hc;
      hc = fmaf(v[j].x, hc, v[j].y);
    }
  }
}

// Phase C: replay. 1024 blocks x 256 thr (16 waves/CU). Wave g of a block
// owns subchunk g of the chunk: fold <=3 pqsub summaries onto the chunk's
// starting h (wave-uniform branch), then 16-step replay; 4 ch/thread,
// uint4 loads / float4 stores (16B/lane, coalesced).
__global__ __launch_bounds__(256) void scan_phaseC(
    const uint* __restrict__ ab, const float* __restrict__ hstate,
    const float2* __restrict__ pqsub, float* __restrict__ out)
{
  const int cid = blockIdx.x;           // global chunk id
  const int b = cid >> 7;
  const int c = cid & (CHUNKS - 1);
  const int g = threadIdx.x >> 6;       // subchunk 0..3 (== wave id)
  const int ch4 = (threadIdx.x & 63) * 4;

  float4 h4 = *(const float4*)(hstate + ((size_t)b * CHUNKS + c) * H_ + ch4);
  float h0v = h4.x, h1v = h4.y, h2v = h4.z, h3v = h4.w;

  // Advance h to the start of subchunk g (wave-uniform trip count).
  const float2* ps = pqsub + ((size_t)b * CHUNKS + c) * 4 * H_ + ch4;
#pragma unroll
  for (int k = 0; k < 3; k++) {
    if (k < g) {
      const float2 p0 = ps[(size_t)k * H_ + 0];
      const float2 p1 = ps[(size_t)k * H_ + 1];
      const float2 p2 = ps[(size_t)k * H_ + 2];
      const float2 p3 = ps[(size_t)k * H_ + 3];
      h0v = fmaf(p0.x, h0v, p0.y);
      h1v = fmaf(p1.x, h1v, p1.y);
      h2v = fmaf(p2.x, h2v, p2.y);
      h3v = fmaf(p3.x, h3v, p3.y);
    }
  }

  const size_t ebase =
      ((size_t)b * S_ + (size_t)c * CLEN + g * 16) * H_ + ch4;
#pragma unroll
  for (int t0 = 0; t0 < 16; t0 += 8) {
    uint4 v[8];
#pragma unroll
    for (int j = 0; j < 8; j++)
      v[j] = *(const uint4*)(ab + ebase + (size_t)(t0 + j) * H_);
#pragma unroll
    for (int j = 0; j < 8; j++) {
      float4 o;
      o.x = h0v = fmaf(a_of(v[j].x), h0v, b_of(v[j].x));
      o.y = h1v = fmaf(a_of(v[j].y), h1v, b_of(v[j].y));
      o.z = h2v = fmaf(a_of(v[j].z), h2v, b_of(v[j].z));
      o.w = h3v = fmaf(a_of(v[j].w), h3v, b_of(v[j].w));
      *(float4*)(out + ebase + (size_t)(t0 + j) * H_) = o;
    }
  }
}

extern "C" void kernel_launch(void* const* d_in, const int* in_sizes, int n_in,
                              void* d_out, int out_size, void* d_ws, size_t ws_size,
                              hipStream_t stream) {
  const float* x   = (const float*)d_in[0];
  const float* h0  = (const float*)d_in[1];
  const float* whw = (const float*)d_in[2];
  const float* whb = (const float*)d_in[3];
  const float* wzw = (const float*)d_in[4];
  const float* wzb = (const float*)d_in[5];
  float* out = (float*)d_out;

  uint*   ab      = (uint*)d_ws;                          // [M,H] packed bf16
  float2* chunkPQ = (float2*)(ab + (size_t)M_ * H_);      // [B,CHUNKS,H]
  float2* pqsub   = chunkPQ + (size_t)B_ * CHUNKS * H_;   // [B,CHUNKS*4,H]
  float*  hstate  = (float*)(pqsub + (size_t)B_ * CHUNKS * 4 * H_);  // [B,CHUNKS,H]
  ushort* wb      = (ushort*)(hstate + (size_t)B_ * CHUNKS * H_);    // [2,H,D] bf16

  prep_w<<<64, 256, 0, stream>>>(wzw, whw, (uint4*)wb);
  gemm_zh<<<(M_ / 128) * (H_ / 128), 512, 0, stream>>>(
      x, wb, whb, wzb, ab, chunkPQ, pqsub);
  scan_phaseB<<<B_, 256, 0, stream>>>(h0, (const float2*)chunkPQ, hstate);
  scan_phaseC<<<B_ * CHUNKS, 256, 0, stream>>>(ab, hstate, pqsub, out);
}

// Round 10
// 176.714 us; speedup vs baseline: 1.0197x; 1.0197x over previous
//
#include <hip/hip_runtime.h>
#include <math.h>

// MinGRU: B=8, S=8192, D=256, H=256, fp32 in/out.  TWO-PASS RECOMPUTE:
//   K0 prep_w   : weights-only fp32->bf16 (256 KiB, ~3 us).
//   K1 gemm_sum : bf16-MFMA dual GEMM (512 thr / 128x128 tile); computes
//                 a=1-z, b=z*h~ per element but stores ONLY per-chunk
//                 (P,Q) summaries (2 MB). No 64 MB ab materialization.
//   K2 phaseB   : sequential scan over 128 chunk summaries -> hstate.
//   K3 gemm_out : RECOMPUTES the same GEMM bit-identically, then an
//                 in-register prefix epilogue (ordered shfl inclusive
//                 prefix over q + lane-local chain over i) produces h for
//                 every t and writes out directly. The 64MB ab write +
//                 64MB ab read (old phaseC) are gone.
// Rationale: R3-R9 showed total-minus-gemm pinned at ~112-121us across 4
// phaseC variants -> phaseC was at its memory floor; MfmaUtil 10% means
// recompute is nearly free. R1/R2: no grid-sync register scans (spills).
// R4: composition at sub-chunk granularity numerically validated.

constexpr int B_ = 8;
constexpr int S_ = 8192;
constexpr int D_ = 256;
constexpr int H_ = 256;
constexpr int M_ = B_ * S_;        // 65536 rows
constexpr int CHUNKS = 128;
constexpr int CLEN = S_ / CHUNKS;  // 64

typedef __attribute__((ext_vector_type(8))) short bf16x8;
typedef __attribute__((ext_vector_type(4))) float f32x4;

// 2 floats -> 2 bf16 (round-to-nearest, ties-away): 2 adds + 1 v_perm.
__device__ __forceinline__ uint pack2bf(float f0, float f1) {
  const uint u0 = __float_as_uint(f0) + 0x8000u;
  const uint u1 = __float_as_uint(f1) + 0x8000u;
  return __builtin_amdgcn_perm(u1, u0, 0x07060302u);
}

__device__ __forceinline__ float a_of(uint u) { return __uint_as_float(u << 16); }
__device__ __forceinline__ float b_of(uint u) { return __uint_as_float(u & 0xFFFF0000u); }

// ---------------------------------------------------------------- prep ----
__global__ __launch_bounds__(256) void prep_w(
    const float* __restrict__ wzw, const float* __restrict__ whw,
    uint4* __restrict__ wb)
{
  const int u = blockIdx.x * 256 + threadIdx.x;   // 0..16383 (8192 per proj)
  const int proj = u >> 13;
  const float* s = (proj ? whw : wzw) + (size_t)(u & 8191) * 8;
  wb[u] = make_uint4(pack2bf(s[0], s[1]), pack2bf(s[2], s[3]),
                     pack2bf(s[4], s[5]), pack2bf(s[6], s[7]));
}

// ------------------------------------------------------- shared GEMM body --
// Block: 512 thr = 8 waves. Tile: 128 rows x 128 ch, both projections.
// LDS rows padded to 72 bf16 (144B: uint4-aligned, conflict-free b128).
// Wave w: rows mb..mb+63 (one 64-step chunk), channels nb..nb+31.
#define GEMM_PREAMBLE(xptr, wptr)                                            \
  __shared__ ushort xs[128][72];                                             \
  __shared__ ushort wzs[128][72];                                            \
  __shared__ ushort whs[128][72];                                            \
  const int tid = threadIdx.x;                                               \
  const int g    = blockIdx.x;                                               \
  const int xcd  = g & 7;                                                    \
  const int loc  = g >> 3;                                                   \
  const int nt   = loc & 1;                                                  \
  const int panel = (loc >> 1) * 8 + xcd;                                    \
  const int m0 = panel * 128;                                                \
  const int n0 = nt * 128;                                                   \
  const int lane = tid & 63;                                                 \
  const int w  = tid >> 6;                                                   \
  const int mb = (w & 1) * 64;                                               \
  const int nb = (w >> 1) * 32;                                              \
  const int q  = lane >> 4;                                                  \
  const int cn = lane & 15;                                                  \
  f32x4 accz[4][2] = {};                                                     \
  f32x4 acch[4][2] = {};                                                     \
  for (int k0 = 0; k0 < D_; k0 += 64) {                                      \
    __syncthreads();                                                         \
    _Pragma("unroll")                                                        \
    for (int f = 0; f < 4; f++) {                                            \
      const int idx = tid + 512 * f;                                         \
      const int row = idx >> 4, seg = idx & 15;                              \
      float4 v = *(const float4*)(xptr + (size_t)(m0 + row) * D_ + k0 + seg * 4); \
      *(uint2*)&xs[row][seg * 4] =                                           \
          make_uint2(pack2bf(v.x, v.y), pack2bf(v.z, v.w));                  \
    }                                                                        \
    _Pragma("unroll")                                                        \
    for (int f = 0; f < 4; f++) {                                            \
      const int idx = tid + 512 * f;                                         \
      const int proj = idx >> 10;                                            \
      const int r   = (idx >> 3) & 127, seg = idx & 7;                       \
      const uint4 v = *(const uint4*)(wptr + (size_t)proj * H_ * D_ +        \
                                      (size_t)(n0 + r) * D_ + k0 + seg * 8); \
      ushort* dst = proj ? &whs[r][seg * 8] : &wzs[r][seg * 8];              \
      *(uint4*)dst = v;                                                      \
    }                                                                        \
    __syncthreads();                                                         \
    _Pragma("unroll")                                                        \
    for (int ks = 0; ks < 2; ks++) {                                         \
      const int kk = ks * 32 + q * 8;                                        \
      bf16x8 af[4], bz[2], bh[2];                                            \
      _Pragma("unroll")                                                      \
      for (int i = 0; i < 4; i++)                                            \
        af[i] = *(const bf16x8*)&xs[mb + i * 16 + cn][kk];                   \
      _Pragma("unroll")                                                      \
      for (int j = 0; j < 2; j++) {                                          \
        bz[j] = *(const bf16x8*)&wzs[nb + j * 16 + cn][kk];                  \
        bh[j] = *(const bf16x8*)&whs[nb + j * 16 + cn][kk];                  \
      }                                                                      \
      _Pragma("unroll")                                                      \
      for (int i = 0; i < 4; i++)                                            \
        _Pragma("unroll")                                                    \
        for (int j = 0; j < 2; j++) {                                        \
          accz[i][j] = __builtin_amdgcn_mfma_f32_16x16x32_bf16(af[i], bz[j], accz[i][j], 0, 0, 0); \
          acch[i][j] = __builtin_amdgcn_mfma_f32_16x16x32_bf16(af[i], bh[j], acch[i][j], 0, 0, 0); \
        }                                                                    \
    }                                                                        \
  }                                                                          \
  const int row0 = m0 + mb;                                                  \
  const int bb2  = row0 >> 13;                                               \
  const int cc   = (row0 & 8191) >> 6;

// --------------------------------------------------------------- pass 1 ---
// Chunk summaries only. t within chunk = i*16 + q*4 + r.
__global__ __launch_bounds__(512, 4) void gemm_sum(
    const float* __restrict__ x, const ushort* __restrict__ wbu,
    const float* __restrict__ whb, const float* __restrict__ wzb,
    float2* __restrict__ chunkPQ)
{
  GEMM_PREAMBLE(x, wbu)

#pragma unroll
  for (int j = 0; j < 2; j++) {
    const int ch = n0 + nb + j * 16 + cn;
    const float zb = wzb[ch], hb = whb[ch];
    float P[4], Q[4];
#pragma unroll
    for (int i = 0; i < 4; i++) {
      float Pi = 1.f, Qi = 0.f;
#pragma unroll
      for (int r = 0; r < 4; r++) {
        const float zpre = accz[i][j][r] + zb;
        const float hpre = acch[i][j][r] + hb;
        const float e = __expf(-zpre);
        const float rcp = __builtin_amdgcn_rcpf(1.0f + e);  // z
        const uint pk = pack2bf(e * rcp, hpre * rcp);  // keep rounding parity
        Qi = fmaf(a_of(pk), Qi, b_of(pk));
        Pi *= a_of(pk);
      }
      P[i] = Pi; Q[i] = Qi;
    }
    // all-reduce over q (t-order aware butterfly), then fold i.
#pragma unroll
    for (int i = 0; i < 4; i++) {
      {
        const float Pp = __shfl_xor(P[i], 16);
        const float Qp = __shfl_xor(Q[i], 16);
        const bool later = (lane & 16) != 0;
        Q[i] = later ? fmaf(P[i], Qp, Q[i]) : fmaf(Pp, Q[i], Qp);
        P[i] = P[i] * Pp;
      }
      {
        const float Pp = __shfl_xor(P[i], 32);
        const float Qp = __shfl_xor(Q[i], 32);
        const bool later = (lane & 32) != 0;
        Q[i] = later ? fmaf(P[i], Qp, Q[i]) : fmaf(Pp, Q[i], Qp);
        P[i] = P[i] * Pp;
      }
    }
    float Pc = P[0], Qc = Q[0];
#pragma unroll
    for (int i = 1; i < 4; i++) {
      Qc = fmaf(P[i], Qc, Q[i]);
      Pc *= P[i];
    }
    if (lane < 16)
      chunkPQ[((size_t)bb2 * CHUNKS + cc) * H_ + ch] = make_float2(Pc, Qc);
  }
}

// --------------------------------------------------------------- phase B --
__global__ __launch_bounds__(256) void scan_phaseB(
    const float* __restrict__ h0in, const float2* __restrict__ pq,
    float* __restrict__ hstate)
{
  const int b = blockIdx.x;
  const int h = threadIdx.x;
  const size_t base = (size_t)b * CHUNKS * H_ + h;
  float hc = h0in[(size_t)b * H_ + h];
  for (int c0 = 0; c0 < CHUNKS; c0 += 16) {
    float2 v[16];
#pragma unroll
    for (int j = 0; j < 16; j++)
      v[j] = pq[base + (size_t)(c0 + j) * H_];
#pragma unroll
    for (int j = 0; j < 16; j++) {
      hstate[base + (size_t)(c0 + j) * H_] = hc;
      hc = fmaf(v[j].x, hc, v[j].y);
    }
  }
}

// --------------------------------------------------------------- pass 2 ---
// Recompute a,b; prefix-scan h in registers; write out directly.
__global__ __launch_bounds__(512, 4) void gemm_out(
    const float* __restrict__ x, const ushort* __restrict__ wbu,
    const float* __restrict__ whb, const float* __restrict__ wzb,
    const float* __restrict__ hstate, float* __restrict__ out)
{
  GEMM_PREAMBLE(x, wbu)

#pragma unroll
  for (int j = 0; j < 2; j++) {
    const int ch = n0 + nb + j * 16 + cn;
    const float zb = wzb[ch], hb = whb[ch];
    uint u[4][4];
    float P[4], Q[4];
#pragma unroll
    for (int i = 0; i < 4; i++) {
      float Pi = 1.f, Qi = 0.f;
#pragma unroll
      for (int r = 0; r < 4; r++) {
        const float zpre = accz[i][j][r] + zb;
        const float hpre = acch[i][j][r] + hb;
        const float e = __expf(-zpre);
        const float rcp = __builtin_amdgcn_rcpf(1.0f + e);  // z
        const uint pk = pack2bf(e * rcp, hpre * rcp);
        u[i][r] = pk;
        Qi = fmaf(a_of(pk), Qi, b_of(pk));
        Pi *= a_of(pk);
      }
      P[i] = Pi; Q[i] = Qi;
    }
    // Ordered INCLUSIVE prefix over q (lanes q*16+cn; earlier q = earlier t).
    // Hillis-Steele d=1,2: cur = comb(recv_from_earlier, cur):
    //   P = P*Pr ; Q = fma(P, Qr, Q).
#pragma unroll
    for (int i = 0; i < 4; i++) {
#pragma unroll
      for (int d = 1; d <= 2; d++) {
        const int src = (q >= d) ? (lane - 16 * d) : lane;
        const float Pp = __shfl(P[i], src);
        const float Qp = __shfl(Q[i], src);
        if (q >= d) {
          Q[i] = fmaf(P[i], Qp, Q[i]);
          P[i] = P[i] * Pp;
        }
      }
    }
    // h at chunk start for this channel.
    float hst = hstate[((size_t)bb2 * CHUNKS + cc) * H_ + ch];
#pragma unroll
    for (int i = 0; i < 4; i++) {
      // subchunk-i total: q=3's inclusive value (lane cn+48).
      const float Tp = __shfl(P[i], cn + 48);
      const float Tq = __shfl(Q[i], cn + 48);
      // exclusive prefix for this lane: q-1's inclusive, identity at q=0.
      const float Ps = __shfl(P[i], (q > 0) ? (lane - 16) : lane);
      const float Qs = __shfl(Q[i], (q > 0) ? (lane - 16) : lane);
      const float Pe = (q == 0) ? 1.f : Ps;
      const float Qe = (q == 0) ? 0.f : Qs;
      // h at t = i*16 + q*4, then 4-step replay with direct store.
      float hcur = fmaf(Pe, hst, Qe);
#pragma unroll
      for (int r = 0; r < 4; r++) {
        hcur = fmaf(a_of(u[i][r]), hcur, b_of(u[i][r]));
        out[(size_t)(m0 + mb + i * 16 + q * 4 + r) * H_ + ch] = hcur;
      }
      // advance chunk-start h past subchunk i (all lanes, uniform per cn).
      hst = fmaf(Tp, hst, Tq);
    }
  }
}

extern "C" void kernel_launch(void* const* d_in, const int* in_sizes, int n_in,
                              void* d_out, int out_size, void* d_ws, size_t ws_size,
                              hipStream_t stream) {
  const float* x   = (const float*)d_in[0];
  const float* h0  = (const float*)d_in[1];
  const float* whw = (const float*)d_in[2];
  const float* whb = (const float*)d_in[3];
  const float* wzw = (const float*)d_in[4];
  const float* wzb = (const float*)d_in[5];
  float* out = (float*)d_out;

  float2* chunkPQ = (float2*)d_ws;                        // [B,CHUNKS,H]
  float*  hstate  = (float*)(chunkPQ + (size_t)B_ * CHUNKS * H_);  // [B,CHUNKS,H]
  ushort* wb      = (ushort*)(hstate + (size_t)B_ * CHUNKS * H_);  // [2,H,D] bf16

  prep_w<<<64, 256, 0, stream>>>(wzw, whw, (uint4*)wb);
  gemm_sum<<<(M_ / 128) * (H_ / 128), 512, 0, stream>>>(
      x, wb, whb, wzb, chunkPQ);
  scan_phaseB<<<B_, 256, 0, stream>>>(h0, (const float2*)chunkPQ, hstate);
  gemm_out<<<(M_ / 128) * (H_ / 128), 512, 0, stream>>>(
      x, wb, whb, wzb, hstate, out);
}